// Round 2
// baseline (302.010 us; speedup 1.0000x reference)
//
#include <hip/hip_runtime.h>

// MultiScaleWaveletBlock: 3-level Haar DWT along T + linear upsample of the
// 3 detail bands + final approx back to T, stacked on a new last axis.
// x: (B=16, T=2048, C=512) f32.  out: (B, T, C, 4) f32.
//
// One thread = one (b, c, t-group-of-8). Loads the 24-input halo window,
// computes the local Haar tree in registers, writes 8 float4 outputs.
// All interpolation indices/weights are compile-time constants (T%8==0, so
// the reference's odd-length padding never triggers and src/w are exact
// multiples of 1/16 in fp32 -> bit-identical weights in the interior).
// Boundary groups replicate the edge band value into the out-of-range
// slot, which reproduces the reference's index clamp to <=1 ulp.

#define BB 16
#define TT 2048
#define CC 512
#define NG (TT / 8)   // 256 groups of 8 along t

__global__ __launch_bounds__(256) void msw_kernel(const float* __restrict__ x,
                                                  float* __restrict__ out) {
    const int tid  = blockIdx.x * blockDim.x + threadIdx.x;
    const int c    = tid & (CC - 1);        // lanes consecutive in c -> coalesced
    const int rest = tid >> 9;
    const int g    = rest & (NG - 1);
    const int b    = rest >> 8;

    const float HC = 0.70710678118654752440f;  // 1/sqrt(2), rounds to same f32 as ref

    const float* xp = x + (size_t)b * TT * CC + c;
    const int t0 = g * 8 - 8;

    // ---- load 24-input halo window (t in [8g-8, 8g+16), clamped) ----
    float in[24];
#pragma unroll
    for (int i = 0; i < 24; ++i) {
        int t = t0 + i;
        t = t < 0 ? 0 : (t > TT - 1 ? TT - 1 : t);
        in[i] = xp[(size_t)t * CC];
    }

    // ---- local Haar tree ----
    // a1[j]: level-1 approx, global idx 4g-4+j, j=0..11
    // d1[k]: level-1 detail, global idx 4g-1+k, k=0..5  (inputs local 2k+6, 2k+7)
    float a1[12], d1[6];
#pragma unroll
    for (int j = 0; j < 12; ++j) a1[j] = (in[2 * j] + in[2 * j + 1]) * HC;
#pragma unroll
    for (int k = 0; k < 6; ++k)  d1[k] = (in[2 * k + 6] - in[2 * k + 7]) * HC;

    // a2[m]: level-2 approx, global 2g-2+m, m=0..5 (a1 local 2m, 2m+1)
    // d2[k]: level-2 detail, global 2g-1+k, k=0..3 (a1 local 2k+2, 2k+3)
    float a2[6], d2[4];
#pragma unroll
    for (int m = 0; m < 6; ++m) a2[m] = (a1[2 * m] + a1[2 * m + 1]) * HC;
#pragma unroll
    for (int k = 0; k < 4; ++k) d2[k] = (a1[2 * k + 2] - a1[2 * k + 3]) * HC;

    // a3/d3[n]: level-3, global g-1+n, n=0..2 (a2 local 2n, 2n+1)
    float a3[3], d3[3];
#pragma unroll
    for (int n = 0; n < 3; ++n) {
        a3[n] = (a2[2 * n] + a2[2 * n + 1]) * HC;
        d3[n] = (a2[2 * n] - a2[2 * n + 1]) * HC;
    }

    // ---- edge replication (reproduces reference's index clamping) ----
    if (g == 0)      { d1[0] = d1[1]; d2[0] = d2[1]; d3[0] = d3[1]; a3[0] = a3[1]; }
    if (g == NG - 1) { d1[5] = d1[4]; d2[3] = d2[2]; d3[2] = d3[1]; a3[2] = a3[1]; }

    // ---- interpolation tables (all compile-time after unroll) ----
    // band0 (L=1024): pair (k1, k1+1), w
    const int   k1[8] = {0, 1, 1, 2, 2, 3, 3, 4};
    const float w1[8] = {0.75f, 0.25f, 0.75f, 0.25f, 0.75f, 0.25f, 0.75f, 0.25f};
    // band1 (L=512)
    const int   k2[8] = {0, 0, 1, 1, 1, 1, 2, 2};
    const float w2[8] = {5 / 8.f, 7 / 8.f, 1 / 8.f, 3 / 8.f, 5 / 8.f, 7 / 8.f, 1 / 8.f, 3 / 8.f};
    // band2/3 (L=256)
    const int   k3[8] = {0, 0, 0, 0, 1, 1, 1, 1};
    const float w3[8] = {9 / 16.f, 11 / 16.f, 13 / 16.f, 15 / 16.f,
                         1 / 16.f, 3 / 16.f, 5 / 16.f, 7 / 16.f};

    float4* op = (float4*)out + ((size_t)b * TT + (size_t)g * 8) * CC + c;
#pragma unroll
    for (int dt = 0; dt < 8; ++dt) {
        const float v0 = d1[k1[dt]] * (1.0f - w1[dt]) + d1[k1[dt] + 1] * w1[dt];
        const float v1 = d2[k2[dt]] * (1.0f - w2[dt]) + d2[k2[dt] + 1] * w2[dt];
        const float v2 = d3[k3[dt]] * (1.0f - w3[dt]) + d3[k3[dt] + 1] * w3[dt];
        const float v3 = a3[k3[dt]] * (1.0f - w3[dt]) + a3[k3[dt] + 1] * w3[dt];
        op[(size_t)dt * CC] = make_float4(v0, v1, v2, v3);
    }
}

extern "C" void kernel_launch(void* const* d_in, const int* in_sizes, int n_in,
                              void* d_out, int out_size, void* d_ws, size_t ws_size,
                              hipStream_t stream) {
    const float* x = (const float*)d_in[0];
    float* out = (float*)d_out;
    const int total = BB * NG * CC;          // 2,097,152 threads
    const int block = 256;
    const int grid = total / block;          // 8192 blocks
    msw_kernel<<<grid, block, 0, stream>>>(x, out);
}